// Round 5
// baseline (49.348 us; speedup 1.0000x reference)
//
#include <hip/hip_runtime.h>
#include <hip/hip_bf16.h>

typedef __attribute__((ext_vector_type(8))) short s8x8;
typedef __attribute__((ext_vector_type(4))) float f32x4;

__device__ __forceinline__ ushort f2bf(float x) {
    union { float f; unsigned u; } c; c.f = x;
    unsigned r = c.u + 0x7FFFu + ((c.u >> 16) & 1u);
    return (ushort)(r >> 16);
}
__device__ __forceinline__ float bf2f(ushort b) {
    union { unsigned u; float f; } c; c.u = ((unsigned)b) << 16;
    return c.f;
}

// ---------------------------------------------------------------------------
// Kernel 0: prep — convert X (3x 1536x256 fp32) to bf16 hi/lo row-major, and
// W (3x 256x256 fp32) to bf16 hi/lo in B-frag-native global layout:
//   WB[z][ ((kk*4+lg)*256 + col)*8 + j ] = W[z][col][kk*32+lg*8+j]
// grid 1344 x 256, one float4 per thread.
// ---------------------------------------------------------------------------
__global__ __launch_bounds__(256) void prep_kernel(
    const float* __restrict__ Xq, const float* __restrict__ Xk,
    const float* __restrict__ Xv,
    const float* __restrict__ Wq, const float* __restrict__ Wk,
    const float* __restrict__ Wv,
    ushort* __restrict__ xh, ushort* __restrict__ xl,
    ushort* __restrict__ wbh, ushort* __restrict__ wbl)
{
    const int id = blockIdx.x * 256 + threadIdx.x;
    if (id < 294912) {           // X path: 3 * 98304 float4
        const int z = id / 98304;
        const int r = id - z * 98304;
        const float* X = (z == 0) ? Xq : (z == 1) ? Xk : Xv;
        const float4 v = *(const float4*)&X[(size_t)r * 4];
        const float vv[4] = {v.x, v.y, v.z, v.w};
        unsigned h0 = 0, h1 = 0, l0 = 0, l1 = 0;
        {
            const ushort a0 = f2bf(vv[0]), a1 = f2bf(vv[1]);
            const ushort a2 = f2bf(vv[2]), a3 = f2bf(vv[3]);
            h0 = (unsigned)a0 | ((unsigned)a1 << 16);
            h1 = (unsigned)a2 | ((unsigned)a3 << 16);
            const ushort b0 = f2bf(vv[0] - bf2f(a0)), b1 = f2bf(vv[1] - bf2f(a1));
            const ushort b2 = f2bf(vv[2] - bf2f(a2)), b3 = f2bf(vv[3] - bf2f(a3));
            l0 = (unsigned)b0 | ((unsigned)b1 << 16);
            l1 = (unsigned)b2 | ((unsigned)b3 << 16);
        }
        const size_t dst = (size_t)z * 393216 + (size_t)r * 4;
        *(uint2*)&xh[dst] = make_uint2(h0, h1);
        *(uint2*)&xl[dst] = make_uint2(l0, l1);
    } else if (id < 344064) {    // W path: 3 * 16384 float4
        const int wid = id - 294912;
        const int z = wid / 16384;
        const int r = wid - z * 16384;
        const int col = r >> 6;
        const int k4 = (r & 63) * 4;
        const float* W = (z == 0) ? Wq : (z == 1) ? Wk : Wv;
        const float4 v = *(const float4*)&W[(size_t)col * 256 + k4];
        const float vv[4] = {v.x, v.y, v.z, v.w};
        const int kk = k4 >> 5;
        const int lg = (k4 >> 3) & 3;
        const int j0 = k4 & 7;
        unsigned h0, h1, l0, l1;
        {
            const ushort a0 = f2bf(vv[0]), a1 = f2bf(vv[1]);
            const ushort a2 = f2bf(vv[2]), a3 = f2bf(vv[3]);
            h0 = (unsigned)a0 | ((unsigned)a1 << 16);
            h1 = (unsigned)a2 | ((unsigned)a3 << 16);
            const ushort b0 = f2bf(vv[0] - bf2f(a0)), b1 = f2bf(vv[1] - bf2f(a1));
            const ushort b2 = f2bf(vv[2] - bf2f(a2)), b3 = f2bf(vv[3] - bf2f(a3));
            l0 = (unsigned)b0 | ((unsigned)b1 << 16);
            l1 = (unsigned)b2 | ((unsigned)b3 << 16);
        }
        const size_t dst = (size_t)z * 65536 + ((size_t)((kk * 4 + lg) * 256 + col)) * 8 + j0;
        *(uint2*)&wbh[dst] = make_uint2(h0, h1);
        *(uint2*)&wbl[dst] = make_uint2(l0, l1);
    }
}

// ---------------------------------------------------------------------------
// Kernel 1: proj GEMM  Y = X*W^T + b, all-bf16 operands from prep, NO LDS.
// grid (24, 4, 3), block 256 = 4 waves; wave tile = 16 rows x 64 cols.
// 3-term MFMA hi/lo. Outputs:
//   z=0 q: qh/ql [(a*8+h)*384+n]*32+c
//   z=1 k: kh/kl [((e*8+h)*4+(c>>3))*384+m]*8+(c&7)
//   z=2 v: vh    [(e*8+h)*32+c]*384+m   (packed uint2 stores, hi only)
// ---------------------------------------------------------------------------
__global__ __launch_bounds__(256) void proj_kernel(
    const ushort* __restrict__ xh, const ushort* __restrict__ xl,
    const ushort* __restrict__ wbh, const ushort* __restrict__ wbl,
    const float* __restrict__ bq, const float* __restrict__ bk,
    const float* __restrict__ bv,
    ushort* __restrict__ qh, ushort* __restrict__ ql,
    ushort* __restrict__ kh, ushort* __restrict__ kl,
    ushort* __restrict__ vh)
{
    const int z = blockIdx.z;
    const float* bias = (z == 0) ? bq : (z == 1) ? bk : bv;
    const int tid = threadIdx.x;
    const int wave = tid >> 6;
    const int lane = tid & 63;
    const int lg = lane >> 4;
    const int ll = lane & 15;
    const int bx = blockIdx.x;
    const int by = blockIdx.y;

    const ushort* xhz = xh + (size_t)z * 393216;
    const ushort* xlz = xl + (size_t)z * 393216;
    const ushort* wbhz = wbh + (size_t)z * 65536;
    const ushort* wblz = wbl + (size_t)z * 65536;
    const int rbase = bx * 64 + wave * 16;

    f32x4 acc[4];
    #pragma unroll
    for (int ct = 0; ct < 4; ++ct) acc[ct] = (f32x4){0.f, 0.f, 0.f, 0.f};

    #pragma unroll
    for (int kk = 0; kk < 8; ++kk) {
        const size_t aoff = (size_t)(rbase + ll) * 256 + kk * 32 + lg * 8;
        const s8x8 axh = *(const s8x8*)&xhz[aoff];
        const s8x8 axl = *(const s8x8*)&xlz[aoff];
        #pragma unroll
        for (int ct = 0; ct < 4; ++ct) {
            const size_t boff = ((size_t)((kk * 4 + lg) * 256 + by * 64 + ct * 16 + ll)) * 8;
            const s8x8 bh = *(const s8x8*)&wbhz[boff];
            const s8x8 bl = *(const s8x8*)&wblz[boff];
            acc[ct] = __builtin_amdgcn_mfma_f32_16x16x32_bf16(axh, bh, acc[ct], 0, 0, 0);
            acc[ct] = __builtin_amdgcn_mfma_f32_16x16x32_bf16(axl, bh, acc[ct], 0, 0, 0);
            acc[ct] = __builtin_amdgcn_mfma_f32_16x16x32_bf16(axh, bl, acc[ct], 0, 0, 0);
        }
    }

    const int ae = bx / 6;                       // a (q) or e (k,v)
    const int nbase = (bx - ae * 6) * 64 + wave * 16 + lg * 4;

    if (z != 2) {
        #pragma unroll
        for (int ct = 0; ct < 4; ++ct) {
            const float bb = bias[by * 64 + ct * 16 + ll];
            const int hsel = by * 2 + (ct >> 1);
            const int csel = (ct & 1) * 16 + ll;
            #pragma unroll
            for (int j = 0; j < 4; ++j) {
                const int n = nbase + j;
                const float v = acc[ct][j] + bb;
                const ushort hb = f2bf(v);
                const ushort lb = f2bf(v - bf2f(hb));
                if (z == 0) {
                    const size_t idx = ((size_t)((ae * 8 + hsel) * 384 + n)) * 32 + csel;
                    qh[idx] = hb; ql[idx] = lb;
                } else {
                    const size_t idx =
                        ((size_t)(((ae * 8 + hsel) * 4 + (csel >> 3)) * 384 + n)) * 8 + (csel & 7);
                    kh[idx] = hb; kl[idx] = lb;
                }
            }
        }
    } else {
        #pragma unroll
        for (int ct = 0; ct < 4; ++ct) {
            const float bb = bias[by * 64 + ct * 16 + ll];
            const int hsel = by * 2 + (ct >> 1);
            const int csel = (ct & 1) * 16 + ll;
            ushort p[4];
            #pragma unroll
            for (int j = 0; j < 4; ++j) p[j] = f2bf(acc[ct][j] + bb);
            const unsigned u0 = (unsigned)p[0] | ((unsigned)p[1] << 16);
            const unsigned u1 = (unsigned)p[2] | ((unsigned)p[3] << 16);
            const size_t basei = ((size_t)((ae * 8 + hsel) * 32 + csel)) * 384 + nbase;
            *(uint2*)&vh[basei] = make_uint2(u0, u1);
        }
    }
}

// ---------------------------------------------------------------------------
// Kernel 2: MFMA flash attention per (a,e,h) x n-strip(96).
// grid (4, 128), block 192 (3 waves, 2 row-tiles of 16 each).
// m in two staged halves of 192. No online max (|s*sc| bounded ~6).
// 3-term hi/lo QK^T (feeds sensitive pooled stats); PV single-term with
// bf16 P staged in LDS in A-frag layout. Writes normalized S + rawsum.
// ---------------------------------------------------------------------------
__global__ __launch_bounds__(192) void attn_mfma_kernel(
    const ushort* __restrict__ qhb, const ushort* __restrict__ qlb,
    const ushort* __restrict__ khb, const ushort* __restrict__ klb,
    const ushort* __restrict__ vhb,
    float* __restrict__ Sout, float* __restrict__ msum_part)
{
    __shared__ ushort Kh[4 * 1544];      // [kblk][m:192][8] + 8-pad per kblk
    __shared__ ushort Kl[4 * 1544];
    __shared__ ushort Vh[32 * 200];      // [c][m:192] + pad
    __shared__ ushort Pl[3 * 2 * 16 * 40];  // [wave][r][n:16][m:32 +pad]
    __shared__ float  red[192];

    const int strip = blockIdx.x;
    const int aeh   = blockIdx.y;          // a*32 + e*8 + h
    const int hh    = aeh & 7;
    const int ee    = (aeh >> 3) & 3;
    const int aa    = aeh >> 5;
    const int e8h   = ee * 8 + hh;
    const int a8h   = aa * 8 + hh;
    const int tid   = threadIdx.x;
    const int wave  = tid >> 6;
    const int lane  = tid & 63;
    const int lg    = lane >> 4;
    const int ll    = lane & 15;

    s8x8 qfh[2], qfl[2];
    #pragma unroll
    for (int r = 0; r < 2; ++r) {
        const int n0 = strip * 96 + (2 * wave + r) * 16;
        const size_t off = (size_t)(a8h * 384 + n0 + ll) * 32 + lg * 8;
        qfh[r] = *(const s8x8*)&qhb[off];
        qfl[r] = *(const s8x8*)&qlb[off];
    }

    f32x4 oacc[2][2];
    #pragma unroll
    for (int r = 0; r < 2; ++r)
        #pragma unroll
        for (int ct = 0; ct < 2; ++ct)
            oacc[r][ct] = (f32x4){0.f, 0.f, 0.f, 0.f};
    float lsum[2][4];
    #pragma unroll
    for (int r = 0; r < 2; ++r)
        #pragma unroll
        for (int j = 0; j < 4; ++j) lsum[r][j] = 0.f;
    float rs = 0.f;
    const float sc = 0.17677669529663687f; // 1/sqrt(32)

    for (int half = 0; half < 2; ++half) {
        #pragma unroll
        for (int i = 0; i < 4; ++i) {
            const size_t src = ((size_t)(e8h * 4 + i) * 384 + half * 192 + tid) * 8;
            *(uint4*)&Kh[i * 1544 + tid * 8] = *(const uint4*)&khb[src];
            *(uint4*)&Kl[i * 1544 + tid * 8] = *(const uint4*)&klb[src];
        }
        #pragma unroll
        for (int i = 0; i < 4; ++i) {
            const int u = tid + 192 * i;
            const int c = u / 24;
            const int m8 = (u - c * 24) * 8;
            *(uint4*)&Vh[c * 200 + m8] =
                *(const uint4*)&vhb[(size_t)(e8h * 32 + c) * 384 + half * 192 + m8];
        }
        __syncthreads();

        for (int mt2 = 0; mt2 < 6; ++mt2) {
            #pragma unroll
            for (int sub = 0; sub < 2; ++sub) {
                const int mt = mt2 * 2 + sub;
                const s8x8 kfh = *(const s8x8*)&Kh[lg * 1544 + (mt * 16 + ll) * 8];
                const s8x8 kfl = *(const s8x8*)&Kl[lg * 1544 + (mt * 16 + ll) * 8];
                #pragma unroll
                for (int r = 0; r < 2; ++r) {
                    f32x4 s = {0.f, 0.f, 0.f, 0.f};
                    __builtin_amdgcn_s_setprio(1);
                    s = __builtin_amdgcn_mfma_f32_16x16x32_bf16(qfh[r], kfh, s, 0, 0, 0);
                    s = __builtin_amdgcn_mfma_f32_16x16x32_bf16(qfl[r], kfh, s, 0, 0, 0);
                    s = __builtin_amdgcn_mfma_f32_16x16x32_bf16(qfh[r], kfl, s, 0, 0, 0);
                    __builtin_amdgcn_s_setprio(0);
                    rs += s[0] + s[1] + s[2] + s[3];
                    #pragma unroll
                    for (int j = 0; j < 4; ++j) {
                        const float p = __expf(s[j] * sc);
                        lsum[r][j] += p;
                        Pl[((wave * 2 + r) * 16 + lg * 4 + j) * 40 + sub * 16 + ll] = f2bf(p);
                    }
                }
            }
            const int mloc = mt2 * 32;
            const s8x8 vf0 = *(const s8x8*)&Vh[(0  + ll) * 200 + mloc + lg * 8];
            const s8x8 vf1 = *(const s8x8*)&Vh[(16 + ll) * 200 + mloc + lg * 8];
            #pragma unroll
            for (int r = 0; r < 2; ++r) {
                const s8x8 pa = *(const s8x8*)&Pl[((wave * 2 + r) * 16 + ll) * 40 + lg * 8];
                __builtin_amdgcn_s_setprio(1);
                oacc[r][0] = __builtin_amdgcn_mfma_f32_16x16x32_bf16(pa, vf0, oacc[r][0], 0, 0, 0);
                oacc[r][1] = __builtin_amdgcn_mfma_f32_16x16x32_bf16(pa, vf1, oacc[r][1], 0, 0, 0);
                __builtin_amdgcn_s_setprio(0);
            }
        }
        __syncthreads();
    }

    // finalize: per-row L across the 16 col-lanes, normalize, write S
    #pragma unroll
    for (int r = 0; r < 2; ++r) {
        #pragma unroll
        for (int j = 0; j < 4; ++j) {
            float L = lsum[r][j];
            L += __shfl_xor(L, 1);
            L += __shfl_xor(L, 2);
            L += __shfl_xor(L, 4);
            L += __shfl_xor(L, 8);
            const float invL = 1.f / L;
            const int row = strip * 96 + (2 * wave + r) * 16 + lg * 4 + j;
            const size_t base = (size_t)(aeh * 384 + row) * 32;
            Sout[base + 0  + ll] = oacc[r][0][j] * invL;
            Sout[base + 16 + ll] = oacc[r][1][j] * invL;
        }
    }

    red[tid] = rs * sc;
    __syncthreads();
    for (int off = 96; off >= 3; off >>= 1) {
        if (tid < off) red[tid] += red[tid + off];
        __syncthreads();
    }
    if (tid == 0) msum_part[aeh * 4 + strip] = red[0] + red[1] + red[2];
}

// ---------------------------------------------------------------------------
// Kernel 3: fused stats + combine.
// Each block reduces the 512 rawsum partials -> weights[16] (redundantly),
// then out[a,n,h*32+c] = sum_e w[a,e]*S[(a,e),h,n,c]. grid 384 x 256,
// one float4 of output per thread.
// ---------------------------------------------------------------------------
__global__ __launch_bounds__(256) void combine_kernel(
    const float* __restrict__ S, const float* __restrict__ msum_part,
    float* __restrict__ out)
{
    __shared__ float sh[128];
    __shared__ float cell[16];
    __shared__ float wsh[16];
    const int tid = threadIdx.x;
    if (tid < 128) {
        float s = 0.f;
        #pragma unroll
        for (int j = 0; j < 4; ++j) s += msum_part[tid * 4 + j];
        sh[tid] = s;
    }
    __syncthreads();
    if (tid < 16) {
        const int base = (tid >> 2) * 32 + (tid & 3) * 8; // a*32 + e*8
        float s = 0.f;
        #pragma unroll
        for (int h2 = 0; h2 < 8; ++h2) s += sh[base + h2];
        cell[tid] = s;
    }
    __syncthreads();
    if (tid == 0) {
        const int TR[12][4] = {
            {0,1,2,3},{0,2,3,1},{0,3,1,2},{1,2,0,3},{1,0,3,2},{1,3,2,0},
            {2,3,0,1},{2,0,1,3},{2,1,3,0},{3,1,0,2},{3,0,2,1},{3,2,1,0}};
        const float denom = 4.0f * 8.0f * 384.0f * 384.0f;
        float pos[12];
        float psum = 0.f;
        for (int r = 0; r < 12; ++r) {
            float s = 0.f;
            for (int a2 = 0; a2 < 4; ++a2) s += cell[a2 * 4 + TR[r][a2]];
            const float pooled = s / denom;
            pos[r] = pooled * pooled;
            psum += pos[r];
        }
        float w[16];
        for (int i = 0; i < 16; ++i) w[i] = 0.f;
        const float ip = 1.f / psum;
        for (int r = 0; r < 12; ++r)
            for (int a2 = 0; a2 < 4; ++a2) w[a2 * 4 + TR[r][a2]] += pos[r] * ip;
        for (int i = 0; i < 16; ++i) wsh[i] = w[i];
    }
    __syncthreads();

    const int idx4 = blockIdx.x * 256 + tid;   // 0..98303
    const int a = idx4 / 24576;
    const int rem = idx4 - a * 24576;
    const int n = rem >> 6;
    const int d4 = rem & 63;
    const int h = d4 >> 3;
    const int c0 = (d4 & 7) * 4;
    float4 r = make_float4(0.f, 0.f, 0.f, 0.f);
    #pragma unroll
    for (int e = 0; e < 4; ++e) {
        const float wv = wsh[a * 4 + e];
        const float4 s = *(const float4*)&S[(size_t)(((a * 4 + e) * 8 + h) * 384 + n) * 32 + c0];
        r.x += wv * s.x; r.y += wv * s.y; r.z += wv * s.z; r.w += wv * s.w;
    }
    *(float4*)&out[(size_t)idx4 * 4] = r;
}

// ---------------------------------------------------------------------------
extern "C" void kernel_launch(void* const* d_in, const int* in_sizes, int n_in,
                              void* d_out, int out_size, void* d_ws, size_t ws_size,
                              hipStream_t stream)
{
    const float* in_q = (const float*)d_in[0];
    const float* in_k = (const float*)d_in[1];
    const float* in_v = (const float*)d_in[2];
    const float* Wq   = (const float*)d_in[3];
    const float* bq   = (const float*)d_in[4];
    const float* Wk   = (const float*)d_in[5];
    const float* bk   = (const float*)d_in[6];
    const float* Wv   = (const float*)d_in[7];
    const float* bv   = (const float*)d_in[8];

    char* base = (char*)d_ws;
    // Region A (aliased; disjoint lifetimes within one call):
    //   prep->proj: xh/xl (4.72 MB)   then   attn->combine: Sb (6.29 MB)
    float*  Sb = (float*)base;                 // 1572864 floats
    ushort* xh = (ushort*)base;                // 1179648 ushorts
    ushort* xl = xh + 1179648;                 // 1179648 ushorts (ends 4.72MB)
    char* p2 = base + 6291456;
    ushort* wbh = (ushort*)p2;                 // 196608
    ushort* wbl = wbh + 196608;                // 196608
    ushort* qh  = wbl + 196608;                // 393216
    ushort* ql  = qh + 393216;
    ushort* kh  = ql + 393216;
    ushort* kl  = kh + 393216;
    ushort* vh  = kl + 393216;
    float*  ms  = (float*)(vh + 393216);       // 512 partials
    float*  outp = (float*)d_out;

    prep_kernel<<<1344, 256, 0, stream>>>(in_q, in_k, in_v, Wq, Wk, Wv,
                                          xh, xl, wbh, wbl);
    dim3 pgrid(24, 4, 3);
    proj_kernel<<<pgrid, 256, 0, stream>>>(xh, xl, wbh, wbl, bq, bk, bv,
                                           qh, ql, kh, kl, vh);
    dim3 agrid(4, 128);
    attn_mfma_kernel<<<agrid, 192, 0, stream>>>(qh, ql, kh, kl, vh, Sb, ms);
    combine_kernel<<<384, 256, 0, stream>>>(Sb, ms, outp);
}

// Round 8
// 47.230 us; speedup vs baseline: 1.0449x; 1.0449x over previous
//
#include <hip/hip_runtime.h>
#include <hip/hip_bf16.h>

typedef __attribute__((ext_vector_type(8))) short s8x8;
typedef __attribute__((ext_vector_type(4))) float f32x4;

union FragU { s8x8 v; unsigned d[4]; };

__device__ __forceinline__ ushort f2bf(float x) {   // RTNE single rounding
    union { float f; unsigned u; } c; c.f = x;
    unsigned r = c.u + 0x7FFFu + ((c.u >> 16) & 1u);
    return (ushort)(r >> 16);
}
__device__ __forceinline__ float bf2f(ushort b) {
    union { unsigned u; float f; } c; c.u = ((unsigned)b) << 16;
    return c.f;
}
__device__ __forceinline__ unsigned cvt_pk(float lo, float hi) {
    unsigned r;
    asm("v_cvt_pk_bf16_f32 %0, %1, %2" : "=v"(r) : "v"(lo), "v"(hi));
    return r;
}
__device__ __forceinline__ float asf(unsigned u) {
    union { unsigned u; float f; } c; c.u = u; return c.f;
}

// ---------------------------------------------------------------------------
// Kernel 1: proj GEMM Y = X*W^T + b (z: 0=q,1=k,2=v). No staging LDS.
// grid (12,4,3), block 256 = 4 waves; wave tile = 32 rows x 64 cols.
// X,W fp32 loaded per-lane, converted in-register to bf16 hi/lo (cvt_pk);
// 3-term MFMA internally; outputs rounded to bf16 hi(+lo for q,k):
//   z=0 q: qh/ql [(a*8+h)*384+n]*32+c
//   z=1 k: kh/kl [((e*8+h)*4+(c>>3))*384+m]*8+(c&7)
//   z=2 v: vh    [(e*8+h)*32+c]*384+m   (transposed, packed stores)
// z!=2 also writes exact fp32 column sums (incl. bias) for the pooled stats:
//   part[((z*4+ae)*3 + rbl)*256 + d]  (summed over the block's 128 rows)
// ---------------------------------------------------------------------------
__global__ __launch_bounds__(256) void proj_kernel(
    const float* __restrict__ Xq, const float* __restrict__ Xk,
    const float* __restrict__ Xv,
    const float* __restrict__ Wq, const float* __restrict__ bq,
    const float* __restrict__ Wk, const float* __restrict__ bk,
    const float* __restrict__ Wv, const float* __restrict__ bv,
    ushort* __restrict__ qh, ushort* __restrict__ ql,
    ushort* __restrict__ kh, ushort* __restrict__ kl,
    ushort* __restrict__ vh, float* __restrict__ part)
{
    __shared__ float csum[4][64];

    const int z = blockIdx.z;
    const float* X    = (z == 0) ? Xq : (z == 1) ? Xk : Xv;
    const float* W    = (z == 0) ? Wq : (z == 1) ? Wk : Wv;
    const float* bias = (z == 0) ? bq : (z == 1) ? bk : bv;

    const int tid  = threadIdx.x;
    const int wave = tid >> 6;
    const int lane = tid & 63;
    const int lg   = lane >> 4;
    const int ll   = lane & 15;
    const int row0 = blockIdx.x * 128 + wave * 32;
    const int col0 = blockIdx.y * 64;

    f32x4 acc[2][4];
    #pragma unroll
    for (int rt = 0; rt < 2; ++rt)
        #pragma unroll
        for (int ct = 0; ct < 4; ++ct) acc[rt][ct] = (f32x4){0.f, 0.f, 0.f, 0.f};

    for (int kk = 0; kk < 8; ++kk) {
        FragU ah[2], al[2];
        #pragma unroll
        for (int rt = 0; rt < 2; ++rt) {
            const float* xp = &X[(size_t)(row0 + rt * 16 + ll) * 256 + kk * 32 + lg * 8];
            const float4 x0 = *(const float4*)&xp[0];
            const float4 x1 = *(const float4*)&xp[4];
            const float xv[8] = {x0.x, x0.y, x0.z, x0.w, x1.x, x1.y, x1.z, x1.w};
            #pragma unroll
            for (int i = 0; i < 4; ++i) {
                const unsigned hd = cvt_pk(xv[2 * i], xv[2 * i + 1]);
                ah[rt].d[i] = hd;
                al[rt].d[i] = cvt_pk(xv[2 * i]     - asf(hd << 16),
                                     xv[2 * i + 1] - asf(hd & 0xffff0000u));
            }
        }
        #pragma unroll
        for (int ct = 0; ct < 4; ++ct) {
            const float* wp = &W[(size_t)(col0 + ct * 16 + ll) * 256 + kk * 32 + lg * 8];
            const float4 w0 = *(const float4*)&wp[0];
            const float4 w1 = *(const float4*)&wp[4];
            const float wv[8] = {w0.x, w0.y, w0.z, w0.w, w1.x, w1.y, w1.z, w1.w};
            FragU bh, bl;
            #pragma unroll
            for (int i = 0; i < 4; ++i) {
                const unsigned hd = cvt_pk(wv[2 * i], wv[2 * i + 1]);
                bh.d[i] = hd;
                bl.d[i] = cvt_pk(wv[2 * i]     - asf(hd << 16),
                                 wv[2 * i + 1] - asf(hd & 0xffff0000u));
            }
            #pragma unroll
            for (int rt = 0; rt < 2; ++rt) {
                acc[rt][ct] = __builtin_amdgcn_mfma_f32_16x16x32_bf16(ah[rt].v, bh.v, acc[rt][ct], 0, 0, 0);
                acc[rt][ct] = __builtin_amdgcn_mfma_f32_16x16x32_bf16(al[rt].v, bh.v, acc[rt][ct], 0, 0, 0);
                acc[rt][ct] = __builtin_amdgcn_mfma_f32_16x16x32_bf16(ah[rt].v, bl.v, acc[rt][ct], 0, 0, 0);
            }
        }
    }

    const int bx = blockIdx.x;
    const int ae = bx / 3;                       // a (q) or e (k,v)
    float bct[4];
    #pragma unroll
    for (int ct = 0; ct < 4; ++ct) bct[ct] = bias[col0 + ct * 16 + ll];

    if (z != 2) {
        #pragma unroll
        for (int rt = 0; rt < 2; ++rt) {
            #pragma unroll
            for (int ct = 0; ct < 4; ++ct) {
                const int d = col0 + ct * 16 + ll;
                const int hd = d >> 5;
                const int c = d & 31;
                #pragma unroll
                for (int j = 0; j < 4; ++j) {
                    const int n = (bx - ae * 3) * 128 + wave * 32 + rt * 16 + lg * 4 + j;
                    const float v = acc[rt][ct][j] + bct[ct];
                    const ushort hb = f2bf(v);
                    const ushort lb = f2bf(v - bf2f(hb));
                    if (z == 0) {
                        const size_t idx = ((size_t)((ae * 8 + hd) * 384 + n)) * 32 + c;
                        qh[idx] = hb; ql[idx] = lb;
                    } else {
                        const size_t idx =
                            ((size_t)(((ae * 8 + hd) * 4 + (c >> 3)) * 384 + n)) * 8 + (c & 7);
                        kh[idx] = hb; kl[idx] = lb;
                    }
                }
            }
        }
        // exact fp32 column sums over this block's 128 rows (incl. bias)
        #pragma unroll
        for (int ct = 0; ct < 4; ++ct) {
            float cs = 8.f * bct[ct];
            #pragma unroll
            for (int rt = 0; rt < 2; ++rt)
                #pragma unroll
                for (int j = 0; j < 4; ++j) cs += acc[rt][ct][j];
            cs += __shfl_xor(cs, 16);
            cs += __shfl_xor(cs, 32);
            if (lg == 0) csum[wave][ct * 16 + ll] = cs;
        }
        __syncthreads();
        if (tid < 64) {
            const float s = csum[0][tid] + csum[1][tid] + csum[2][tid] + csum[3][tid];
            part[((size_t)(z * 4 + ae) * 3 + (bx - ae * 3)) * 256 + blockIdx.y * 64 + tid] = s;
        }
    } else {
        #pragma unroll
        for (int rt = 0; rt < 2; ++rt) {
            #pragma unroll
            for (int ct = 0; ct < 4; ++ct) {
                const int d = col0 + ct * 16 + ll;
                const int hd = d >> 5;
                const int c = d & 31;
                ushort p[4];
                #pragma unroll
                for (int j = 0; j < 4; ++j) p[j] = f2bf(acc[rt][ct][j] + bct[ct]);
                const int m0 = (bx - ae * 3) * 128 + wave * 32 + rt * 16 + lg * 4;
                const size_t basei = ((size_t)((ae * 8 + hd) * 32 + c)) * 384 + m0;
                *(uint2*)&vh[basei] =
                    make_uint2((unsigned)p[0] | ((unsigned)p[1] << 16),
                               (unsigned)p[2] | ((unsigned)p[3] << 16));
            }
        }
    }
}

// ---------------------------------------------------------------------------
// Kernel 2: MFMA flash attention per (a,e,h) x n-strip(96).
// EXACT copy of the Round-5-passing attention (3 waves, Kh+Kl staged,
// 3-term hi/lo QK^T, bf16-P single-term PV), rawsum machinery removed
// (pooled stats now come from exact factorized column sums).
// grid (4, 128), block 192.
// ---------------------------------------------------------------------------
__global__ __launch_bounds__(192) void attn_mfma_kernel(
    const ushort* __restrict__ qhb, const ushort* __restrict__ qlb,
    const ushort* __restrict__ khb, const ushort* __restrict__ klb,
    const ushort* __restrict__ vhb, float* __restrict__ Sout)
{
    __shared__ ushort Kh[4 * 1544];      // [kblk][m:192][8] + 8-pad per kblk
    __shared__ ushort Kl[4 * 1544];
    __shared__ ushort Vh[32 * 200];      // [c][m:192] + pad
    __shared__ ushort Pl[3 * 2 * 16 * 40];  // [wave][r][n:16][m:32 +pad]

    const int strip = blockIdx.x;
    const int aeh   = blockIdx.y;          // a*32 + e*8 + h
    const int hh    = aeh & 7;
    const int ee    = (aeh >> 3) & 3;
    const int aa    = aeh >> 5;
    const int e8h   = ee * 8 + hh;
    const int a8h   = aa * 8 + hh;
    const int tid   = threadIdx.x;
    const int wave  = tid >> 6;
    const int lane  = tid & 63;
    const int lg    = lane >> 4;
    const int ll    = lane & 15;

    s8x8 qfh[2], qfl[2];
    #pragma unroll
    for (int r = 0; r < 2; ++r) {
        const int n0 = strip * 96 + (2 * wave + r) * 16;
        const size_t off = (size_t)(a8h * 384 + n0 + ll) * 32 + lg * 8;
        qfh[r] = *(const s8x8*)&qhb[off];
        qfl[r] = *(const s8x8*)&qlb[off];
    }

    f32x4 oacc[2][2];
    #pragma unroll
    for (int r = 0; r < 2; ++r)
        #pragma unroll
        for (int ct = 0; ct < 2; ++ct)
            oacc[r][ct] = (f32x4){0.f, 0.f, 0.f, 0.f};
    float lsum[2][4];
    #pragma unroll
    for (int r = 0; r < 2; ++r)
        #pragma unroll
        for (int j = 0; j < 4; ++j) lsum[r][j] = 0.f;
    const float sc = 0.17677669529663687f; // 1/sqrt(32)

    for (int half = 0; half < 2; ++half) {
        #pragma unroll
        for (int i = 0; i < 4; ++i) {
            const size_t src = ((size_t)(e8h * 4 + i) * 384 + half * 192 + tid) * 8;
            *(uint4*)&Kh[i * 1544 + tid * 8] = *(const uint4*)&khb[src];
            *(uint4*)&Kl[i * 1544 + tid * 8] = *(const uint4*)&klb[src];
        }
        #pragma unroll
        for (int i = 0; i < 4; ++i) {
            const int u = tid + 192 * i;
            const int c = u / 24;
            const int m8 = (u - c * 24) * 8;
            *(uint4*)&Vh[c * 200 + m8] =
                *(const uint4*)&vhb[(size_t)(e8h * 32 + c) * 384 + half * 192 + m8];
        }
        __syncthreads();

        for (int mt2 = 0; mt2 < 6; ++mt2) {
            #pragma unroll
            for (int sub = 0; sub < 2; ++sub) {
                const int mt = mt2 * 2 + sub;
                const s8x8 kfh = *(const s8x8*)&Kh[lg * 1544 + (mt * 16 + ll) * 8];
                const s8x8 kfl = *(const s8x8*)&Kl[lg * 1544 + (mt * 16 + ll) * 8];
                #pragma unroll
                for (int r = 0; r < 2; ++r) {
                    f32x4 s = {0.f, 0.f, 0.f, 0.f};
                    __builtin_amdgcn_s_setprio(1);
                    s = __builtin_amdgcn_mfma_f32_16x16x32_bf16(qfh[r], kfh, s, 0, 0, 0);
                    s = __builtin_amdgcn_mfma_f32_16x16x32_bf16(qfl[r], kfh, s, 0, 0, 0);
                    s = __builtin_amdgcn_mfma_f32_16x16x32_bf16(qfh[r], kfl, s, 0, 0, 0);
                    __builtin_amdgcn_s_setprio(0);
                    #pragma unroll
                    for (int j = 0; j < 4; ++j) {
                        const float p = __expf(s[j] * sc);
                        lsum[r][j] += p;
                        Pl[((wave * 2 + r) * 16 + lg * 4 + j) * 40 + sub * 16 + ll] = f2bf(p);
                    }
                }
            }
            // PV over the 32 freshly produced columns
            const int mloc = mt2 * 32;
            const s8x8 vf0 = *(const s8x8*)&Vh[(0  + ll) * 200 + mloc + lg * 8];
            const s8x8 vf1 = *(const s8x8*)&Vh[(16 + ll) * 200 + mloc + lg * 8];
            #pragma unroll
            for (int r = 0; r < 2; ++r) {
                const s8x8 pa = *(const s8x8*)&Pl[((wave * 2 + r) * 16 + ll) * 40 + lg * 8];
                __builtin_amdgcn_s_setprio(1);
                oacc[r][0] = __builtin_amdgcn_mfma_f32_16x16x32_bf16(pa, vf0, oacc[r][0], 0, 0, 0);
                oacc[r][1] = __builtin_amdgcn_mfma_f32_16x16x32_bf16(pa, vf1, oacc[r][1], 0, 0, 0);
                __builtin_amdgcn_s_setprio(0);
            }
        }
        __syncthreads();
    }

    // finalize: per-row L across the 16 col-lanes, normalize, write S
    #pragma unroll
    for (int r = 0; r < 2; ++r) {
        #pragma unroll
        for (int j = 0; j < 4; ++j) {
            float L = lsum[r][j];
            L += __shfl_xor(L, 1);
            L += __shfl_xor(L, 2);
            L += __shfl_xor(L, 4);
            L += __shfl_xor(L, 8);
            const float invL = 1.f / L;
            const int row = strip * 96 + (2 * wave + r) * 16 + lg * 4 + j;
            const size_t base = (size_t)(aeh * 384 + row) * 32;
            Sout[base + 0  + ll] = oacc[r][0][j] * invL;
            Sout[base + 16 + ll] = oacc[r][1][j] * invL;
        }
    }
}

// ---------------------------------------------------------------------------
// Kernel 3: fused stats + combine.
// cell(a,e) = sc * sum_d Qsum[a][d]*Ksum[e][d] (exact fp32, factorized)
// -> pooled -> attn_r -> w[16]; then the weighted S combine.
// grid 384 x 256, one float4 of output per thread.
// ---------------------------------------------------------------------------
__global__ __launch_bounds__(256) void combine_kernel(
    const float* __restrict__ S, const float* __restrict__ part,
    float* __restrict__ out)
{
    __shared__ float ws4[4][16];
    __shared__ float cellsh[16];
    __shared__ float wsh[16];
    const int tid = threadIdx.x;
    const int lane = tid & 63;
    const int wv = tid >> 6;

    // thread = dimension d (0..255): 3-block partials -> Qsum/Ksum
    float qs[4], ks[4];
    #pragma unroll
    for (int a2 = 0; a2 < 4; ++a2) {
        const float* pq = &part[(size_t)(0 * 4 + a2) * 3 * 256 + tid];
        const float* pk = &part[(size_t)(1 * 4 + a2) * 3 * 256 + tid];
        qs[a2] = pq[0] + pq[256] + pq[512];
        ks[a2] = pk[0] + pk[256] + pk[512];
    }
    #pragma unroll
    for (int i = 0; i < 16; ++i) {
        float v = qs[i >> 2] * ks[i & 3];
        v += __shfl_xor(v, 1);
        v += __shfl_xor(v, 2);
        v += __shfl_xor(v, 4);
        v += __shfl_xor(v, 8);
        v += __shfl_xor(v, 16);
        v += __shfl_xor(v, 32);
        if (lane == 0) ws4[wv][i] = v;
    }
    __syncthreads();
    if (tid < 16)
        cellsh[tid] = 0.17677669529663687f *
            (ws4[0][tid] + ws4[1][tid] + ws4[2][tid] + ws4[3][tid]);
    __syncthreads();
    if (tid == 0) {
        const int TR[12][4] = {
            {0,1,2,3},{0,2,3,1},{0,3,1,2},{1,2,0,3},{1,0,3,2},{1,3,2,0},
            {2,3,0,1},{2,0,1,3},{2,1,3,0},{3,1,0,2},{3,0,2,1},{3,2,1,0}};
        const float denom = 4.0f * 8.0f * 384.0f * 384.0f;
        float pos[12];
        float psum = 0.f;
        for (int r = 0; r < 12; ++r) {
            float s = 0.f;
            for (int a2 = 0; a2 < 4; ++a2) s += cellsh[a2 * 4 + TR[r][a2]];
            const float pooled = s / denom;
            pos[r] = pooled * pooled;
            psum += pos[r];
        }
        float w[16];
        for (int i = 0; i < 16; ++i) w[i] = 0.f;
        const float ip = 1.f / psum;
        for (int r = 0; r < 12; ++r)
            for (int a2 = 0; a2 < 4; ++a2) w[a2 * 4 + TR[r][a2]] += pos[r] * ip;
        for (int i = 0; i < 16; ++i) wsh[i] = w[i];
    }
    __syncthreads();

    const int idx4 = blockIdx.x * 256 + tid;   // 0..98303
    const int a = idx4 / 24576;
    const int rem = idx4 - a * 24576;
    const int n = rem >> 6;
    const int d4 = rem & 63;
    const int h = d4 >> 3;
    const int c0 = (d4 & 7) * 4;
    float4 r = make_float4(0.f, 0.f, 0.f, 0.f);
    #pragma unroll
    for (int e = 0; e < 4; ++e) {
        const float wv2 = wsh[a * 4 + e];
        const float4 s = *(const float4*)&S[(size_t)(((a * 4 + e) * 8 + h) * 384 + n) * 32 + c0];
        r.x += wv2 * s.x; r.y += wv2 * s.y; r.z += wv2 * s.z; r.w += wv2 * s.w;
    }
    *(float4*)&out[(size_t)idx4 * 4] = r;
}

// ---------------------------------------------------------------------------
extern "C" void kernel_launch(void* const* d_in, const int* in_sizes, int n_in,
                              void* d_out, int out_size, void* d_ws, size_t ws_size,
                              hipStream_t stream)
{
    const float* in_q = (const float*)d_in[0];
    const float* in_k = (const float*)d_in[1];
    const float* in_v = (const float*)d_in[2];
    const float* Wq   = (const float*)d_in[3];
    const float* bq   = (const float*)d_in[4];
    const float* Wk   = (const float*)d_in[5];
    const float* bk   = (const float*)d_in[6];
    const float* Wv   = (const float*)d_in[7];
    const float* bv   = (const float*)d_in[8];

    ushort* qh = (ushort*)d_ws;               // 393216
    ushort* ql = qh + 393216;                 // 393216
    ushort* kh = ql + 393216;                 // 393216
    ushort* kl = kh + 393216;                 // 393216
    ushort* vh = kl + 393216;                 // 393216
    float*  Sb = (float*)(vh + 393216);       // 1572864 floats
    float*  pt = Sb + 1572864;                // 6144 floats (column sums)
    float*  outp = (float*)d_out;

    dim3 pgrid(12, 4, 3);
    proj_kernel<<<pgrid, 256, 0, stream>>>(in_q, in_k, in_v, Wq, bq, Wk, bk,
                                           Wv, bv, qh, ql, kh, kl, vh, pt);
    dim3 agrid(4, 128);
    attn_mfma_kernel<<<agrid, 192, 0, stream>>>(qh, ql, kh, kl, vh, Sb);
    combine_kernel<<<384, 256, 0, stream>>>(Sb, pt, outp);
}